// Round 14
// baseline (50.430 us; speedup 1.0000x reference)
//
#include <hip/hip_runtime.h>
#include <math.h>

#define Bsz 8
#define Kc 4
#define Nn 16
#define Ss 64
#define Hh 512
#define F2 1024   // 2H = per-part K dim

__device__ __forceinline__ float logsigf(float x) {
    return fminf(x, 0.0f) - log1pf(expf(-fabsf(x)));
}

// ---- DPP wave64 inclusive scans ----
template<int Ctrl, int RowMask>
__device__ __forceinline__ float dpp_add(float x) {
    int v = __builtin_amdgcn_update_dpp(0, __float_as_int(x), Ctrl, RowMask, 0xf, false);
    return x + __int_as_float(v);
}
template<int Ctrl, int RowMask>
__device__ __forceinline__ float dpp_max(float x) {
    int v = __builtin_amdgcn_update_dpp(__float_as_int(-INFINITY), __float_as_int(x),
                                        Ctrl, RowMask, 0xf, false);
    return fmaxf(x, __int_as_float(v));
}
__device__ __forceinline__ float wave_scan_add(float x) {
    x = dpp_add<0x111, 0xf>(x); x = dpp_add<0x112, 0xf>(x);
    x = dpp_add<0x114, 0xf>(x); x = dpp_add<0x118, 0xf>(x);
    x = dpp_add<0x142, 0xa>(x); x = dpp_add<0x143, 0xc>(x);
    return x;
}
__device__ __forceinline__ float wave_scan_max(float x) {
    x = dpp_max<0x111, 0xf>(x); x = dpp_max<0x112, 0xf>(x);
    x = dpp_max<0x114, 0xf>(x); x = dpp_max<0x118, 0xf>(x);
    x = dpp_max<0x142, 0xa>(x); x = dpp_max<0x143, 0xc>(x);
    return x;
}

// ---------------- K1: GEMM — XCD-clustered, 2 blocks/CU, depth-2 A prefetch ----
// grid 512 (1-D).  xcd = lin&7: z = xcd>>2, xx = (xcd&3)*2+(idx&1), yy = idx>>1
// (0..31) -> per-XCD working set 2 A-tiles (512 KB) + one W1 half (2 MB) < 4 MB L2.
// Tile 64m x 16n, 512 thr = 8 waves; wave w owns K[w*128, w*128+128), 8 steps BK=16.
// A: global->reg, 4 statically-named quad buffers (a0..a3), issued 2 quads ahead
//    (step-aligned mod-4 rotation -> all static indexing).  Microtile 4m x 4n.
// B: private per-wave LDS [2][16][20], double-buffered, barrier-free.
// Epilogue: one barrier, 8-way cross-wave sum through reused LDS.
__global__ __launch_bounds__(512) void gemm_kernel(
    const float* __restrict__ seg, const float* __restrict__ vid,
    const float* __restrict__ W1,
    float* __restrict__ Tfin, float* __restrict__ Vfin)
{
    const int lin = blockIdx.x;
    const int xcd = lin & 7;
    const int idx = lin >> 3;
    const int z   = xcd >> 2;
    const int xx  = (xcd & 3) * 2 + (idx & 1);
    const int yy  = idx >> 1;                    // 0..31
    const float* __restrict__ Amat = z ? vid : seg;
    const float* __restrict__ Bmat = W1 + (z ? (size_t)F2 * Hh : 0);
    float* __restrict__ Out = z ? Vfin : Tfin;
    const int r0 = xx * 64;
    const int n0 = yy * 16;

    const int t = threadIdx.x;
    const int w = t >> 6;
    const int l = t & 63;
    const int kbase = w << 7;                    // w*128

    __shared__ __align__(16) float smem[9216];   // Bs (5120) then epilogue red (9216)
    float* Bs_w = smem + w * 640;                // [2 buf][16 kk][20]

    const int b_kk = l >> 2;                     // 0..15
    const int b_c  = (l & 3) << 2;               // 0,4,8,12
    const int mt   = (l >> 2) << 2;              // 0..60 (4 rows)
    const int nt   = (l & 3) << 2;               // 0,4,8,12

    const float* pR[4];
    #pragma unroll
    for (int i = 0; i < 4; ++i)
        pR[i] = Amat + (size_t)(r0 + mt + i) * F2 + kbase;

    float4 bReg;
    auto loadB = [&](int s) {
        bReg = *reinterpret_cast<const float4*>(
            Bmat + (size_t)(kbase + s * 16 + b_kk) * Hh + n0 + b_c);
    };
    auto writeB = [&](int buf) {
        *reinterpret_cast<float4*>(&Bs_w[buf * 320 + b_kk * 20 + b_c]) = bReg;
    };

    float4 a0[4], a1[4], a2[4], a3[4];           // quad buffers, static names only
    float acc[4][4];
    #pragma unroll
    for (int i = 0; i < 4; ++i)
        #pragma unroll
        for (int j = 0; j < 4; ++j) acc[i][j] = 0.f;

#define LOAD_A(BUF, Q) { \
    const int _q = (Q); \
    _Pragma("unroll") \
    for (int i = 0; i < 4; ++i) \
        BUF[i] = *reinterpret_cast<const float4*>(pR[i] + _q * 4); }

#define QUAD(BUF, CUR, QQ) { \
    _Pragma("unroll") \
    for (int j = 0; j < 4; ++j) { \
        float4 b = *reinterpret_cast<const float4*>( \
            &Bs_w[(CUR) * 320 + ((QQ) * 4 + j) * 20 + nt]); \
        float bv[4] = {b.x, b.y, b.z, b.w}; \
        _Pragma("unroll") \
        for (int i = 0; i < 4; ++i) { \
            const float a = j == 0 ? BUF[i].x : j == 1 ? BUF[i].y \
                          : j == 2 ? BUF[i].z : BUF[i].w; \
            _Pragma("unroll") \
            for (int jj = 0; jj < 4; ++jj) \
                acc[i][jj] = fmaf(a, bv[jj], acc[i][jj]); \
        } } }

    loadB(0); writeB(0); loadB(1);
    LOAD_A(a0, 0);
    LOAD_A(a1, 1);
    #pragma unroll 1
    for (int s = 0; s < 8; ++s) {
        const int cur = s & 1;
        const int q0 = s * 4;
        // quad 0: compute a0, issue q0+2 -> a2
        if (q0 + 2 < 32) LOAD_A(a2, q0 + 2);
        QUAD(a0, cur, 0);
        // quad 1: compute a1, issue q0+3 -> a3
        if (q0 + 3 < 32) LOAD_A(a3, q0 + 3);
        QUAD(a1, cur, 1);
        // quad 2: compute a2, issue q0+4 -> a0
        if (q0 + 4 < 32) LOAD_A(a0, q0 + 4);
        QUAD(a2, cur, 2);
        // quad 3: compute a3, issue q0+5 -> a1
        if (q0 + 5 < 32) LOAD_A(a1, q0 + 5);
        QUAD(a3, cur, 3);
        if (s + 1 < 8) {
            writeB(cur ^ 1);                    // bReg holds B tile s+1
            if (s + 2 < 8) loadB(s + 2);
        }
    }
#undef LOAD_A
#undef QUAD

    // ---- epilogue: 8-way cross-wave reduction through reused LDS ----
    __syncthreads();                             // all B reads done
    float* red = smem;                           // 8 waves x 64 lanes x 18
    #pragma unroll
    for (int i = 0; i < 4; ++i)
        *reinterpret_cast<float4*>(&red[w * 1152 + l * 18 + 4 * i]) =
            make_float4(acc[i][0], acc[i][1], acc[i][2], acc[i][3]);
    __syncthreads();
    {
        // thread t -> output (m = t>>3, n = (t&7)*2), float2
        const int m  = t >> 3;
        const int n2 = t & 7;
        const int lp = ((m >> 2) << 2) | (n2 >> 1);
        const int off = lp * 18 + (m & 3) * 4 + (n2 & 1) * 2;
        float2 o = make_float2(0.f, 0.f);
        #pragma unroll
        for (int p = 0; p < 8; ++p) {
            float2 v = *reinterpret_cast<const float2*>(&red[p * 1152 + off]);
            o.x += v.x; o.y += v.y;
        }
        *reinterpret_cast<float2*>(Out + (size_t)(r0 + m) * Hh + n0 + n2 * 2) = o;
    }
}

// ---------------- K2: combine (validated): logits = w2.relu(T+V+b1)+b2 ----
__global__ __launch_bounds__(256) void combine_kernel(
    const float* __restrict__ Tfin, const float* __restrict__ Vfin,
    const float* __restrict__ b1, const float* __restrict__ w2,
    const float* __restrict__ b2, float* __restrict__ logits)
{
    const int bid = blockIdx.x;
    const int b  = bid >> 6;
    const int sc = (bid >> 3) & 7;
    const int rq = bid & 7;
    const int t = threadIdx.x;
    const int wave = t >> 6, lane = t & 63;
    __shared__ float Vs[8][516];
    {
        const int row = t >> 5;
        const int f0  = t & 31;
        const float* src = Vfin + (size_t)(b * Ss + sc * 8 + row) * Hh;
        #pragma unroll
        for (int j = 0; j < 4; ++j)
            *reinterpret_cast<float4*>(&Vs[row][(f0 + 32 * j) * 4]) =
                *reinterpret_cast<const float4*>(src + (f0 + 32 * j) * 4);
    }
    float w2r[8], b1r[8];
    #pragma unroll
    for (int j = 0; j < 8; ++j) { w2r[j] = w2[lane + 64 * j]; b1r[j] = b1[lane + 64 * j]; }
    const float bias2 = b2[0];
    float tj0[8], tj1[8];
    {
        const int r0i = b * 64 + rq * 8 + wave * 2;
        const float* t0 = Tfin + (size_t)r0i * Hh;
        const float* t1 = t0 + Hh;
        #pragma unroll
        for (int j = 0; j < 8; ++j) {
            tj0[j] = t0[lane + 64 * j] + b1r[j];
            tj1[j] = t1[lane + 64 * j] + b1r[j];
        }
    }
    __syncthreads();
    const int rbase = b * 64 + rq * 8 + wave * 2;
    #pragma unroll
    for (int si = 0; si < 8; ++si) {
        float s0 = 0.f, s1 = 0.f;
        #pragma unroll
        for (int j = 0; j < 8; ++j) {
            const float v = Vs[si][lane + 64 * j];
            s0 = fmaf(fmaxf(tj0[j] + v, 0.f), w2r[j], s0);
            s1 = fmaf(fmaxf(tj1[j] + v, 0.f), w2r[j], s1);
        }
        s0 = wave_scan_add(s0);
        s1 = wave_scan_add(s1);
        if (lane == 63) {
            logits[(size_t)rbase * Ss + sc * 8 + si]       = s0 + bias2;
            logits[(size_t)(rbase + 1) * Ss + sc * 8 + si] = s1 + bias2;
        }
    }
}

// ---------------- K3: DP via DPP prefix-max (validated) ----------------
__global__ __launch_bounds__(256) void dp_kernel(
    const float* __restrict__ logits, const float* __restrict__ labels,
    float* __restrict__ out)
{
    const int b = blockIdx.x;
    const int t = threadIdx.x;
    const int k = t >> 6, rl = t & 63;
    const int sI = 63 - rl;
    __shared__ float lgs[Kc][Nn][Ss];
    __shared__ unsigned long long ch[Kc][Nn];
    __shared__ float bestS[Kc], aggS[Kc];
    __shared__ int alS[Kc][Nn];
    const float* lg = logits + (size_t)((b * Kc + k) * Nn) * Ss;
    float lv[Nn];
    #pragma unroll
    for (int n = 0; n < Nn; ++n) {
        lv[n] = lg[n * Ss + sI];
        lgs[k][n][sI] = lv[n];
    }
    float arr = -100.0f;
    #pragma unroll
    for (int n = Nn - 1; n >= 0; --n) {
        const float L = logsigf(lv[n]);
        const float c = (n == Nn - 1) ? L : (L + arr);
        const bool in_band = (rl <= 63 - n) && (rl >= 15 - n);   // s in [n, 48+n]
        float m = in_band ? c : -INFINITY;
        m = wave_scan_max(m);
        const float row = in_band ? fmaxf(m, -100.0f) : -100.0f;
        float rnA = __int_as_float(__builtin_amdgcn_update_dpp(
            __float_as_int(-1e30f), __float_as_int(row), 0x111, 0xf, 0xf, false));
        float b15 = __int_as_float(__builtin_amdgcn_update_dpp(
            0, __float_as_int(row), 0x142, 0xa, 0xf, false));
        float b31 = __int_as_float(__builtin_amdgcn_update_dpp(
            0, __float_as_int(row), 0x143, 0xc, 0xf, false));
        float rn = ((rl & 15) == 0 && rl != 0) ? ((rl == 32) ? b31 : b15) : rnA;
        unsigned long long mask = __ballot(in_band && (c >= rn));
        if (rl == 0) ch[k][n] = __brevll(mask);
        arr = row;
    }
    const float best = __shfl(arr, 63);
    __syncthreads();
    if (rl == 0) {
        float agg = 0.f;
        int start = 0;
        bool dead = false;
        int alignv[Nn];
        #pragma unroll
        for (int n = 0; n < Nn; ++n) {
            unsigned long long m2 = dead ? 0ull : (ch[k][n] & (~0ull << start));
            if (m2) {
                const int s = __builtin_ctzll(m2);
                agg += lgs[k][n][s];
                alignv[n] = s;
                start = s + 1;
            } else {
                alignv[n] = 0;
                dead = true;
            }
        }
        bestS[k] = best; aggS[k] = agg;
        #pragma unroll
        for (int n = 0; n < Nn; ++n) alS[k][n] = alignv[n];
    }
    __syncthreads();
    if (t == 0) {
        int kb = 0; float bb = bestS[0];
        #pragma unroll
        for (int kk = 1; kk < Kc; ++kk)
            if (bestS[kk] > bb) { bb = bestS[kk]; kb = kk; }
        out[b] = 1.0f / (1.0f + expf(-aggS[kb]));
        out[Bsz + b] = labels[b];
        #pragma unroll
        for (int n = 0; n < Nn; ++n)
            out[2 * Bsz + b * Nn + n] = (float)alS[kb][n];
    }
}

extern "C" void kernel_launch(void* const* d_in, const int* in_sizes, int n_in,
                              void* d_out, int out_size, void* d_ws, size_t ws_size,
                              hipStream_t stream) {
    const float* seg    = (const float*)d_in[0];
    const float* vid    = (const float*)d_in[1];
    const float* labels = (const float*)d_in[2];
    const float* W1     = (const float*)d_in[3];
    const float* b1     = (const float*)d_in[4];
    const float* w2     = (const float*)d_in[5];
    const float* b2     = (const float*)d_in[6];
    float* out = (float*)d_out;

    float* Tfin   = (float*)d_ws;
    float* Vfin   = Tfin + (size_t)512 * Hh;
    float* logits = Vfin + (size_t)512 * Hh;

    hipLaunchKernelGGL(gemm_kernel, dim3(512), dim3(512), 0, stream,
                       seg, vid, W1, Tfin, Vfin);
    hipLaunchKernelGGL(combine_kernel, dim3(512), dim3(256), 0, stream,
                       Tfin, Vfin, b1, w2, b2, logits);
    hipLaunchKernelGGL(dp_kernel, dim3(Bsz), dim3(256), 0, stream, logits, labels, out);
}